// Round 10
// baseline (9754.115 us; speedup 1.0000x reference)
//
#include <hip/hip_runtime.h>
#include <cfloat>
#include <cstdint>

#define N_PTS 16384
#define KNN_K 16
#define KNN_TILE 512
#define CERT_EPS 3e-6f

// ---------------------------------------------------------------------------
// FPS shared block -- SINGLE-BARRIER structure. x,y coord arrays in LDS
// (written once at prologue; winner reads are uniform-address broadcasts).
// Per-wave (key, m2) posted with plain ds_writes into parity double-buffered
// slots (one writer per slot, no atomics, no resets -- R1/R2-validated
// pattern). Certification = global-second-max >= thr (M2-cert, proven
// equivalent to count>1||winner_m2>=thr and HW-validated in R1/R2).
// ---------------------------------------------------------------------------
struct FpsSmem {
    float sx[N_PTS];                 // 64KB: x coords (update loop uses registers)
    float sy[N_PTS];                 // 64KB: y coords
    unsigned long long skey[2][16];  // per-wave packed (m1,~g), parity dbuf
    float sm2v[2][16];               // per-wave exact second max
    int cand_idx[64];
    int cand_cnt;
    int more_flag;
    double red_d[16];
};

// DPP move (VALU pipe). old=v: untargeted lanes keep their own value.
template <int CTRL>
__device__ __forceinline__ unsigned dpp_mov_u32(unsigned v) {
    return (unsigned)__builtin_amdgcn_update_dpp((int)v, (int)v, CTRL, 0xF, 0xF, false);
}

// One top-2 merge step over a DPP move: merges (hi,lo,m2) with the DPP
// neighbor's triple. Key order = R5's atomicMax total order (larger m1,
// tie -> smaller g via lo=~g). m2 update = R2-validated merge rule.
template <int CTRL>
__device__ __forceinline__ void top2_step(unsigned& hi, unsigned& lo, float& m2) {
    const unsigned ohi = dpp_mov_u32<CTRL>(hi);
    const unsigned olo = dpp_mov_u32<CTRL>(lo);
    const float om2 = __uint_as_float(dpp_mov_u32<CTRL>(__float_as_uint(m2)));
    const bool sw = (ohi > hi) || (ohi == hi && olo > lo);
    const float lm1 = __uint_as_float(sw ? hi : ohi);  // loser's max (>=0 always)
    m2 = fmaxf(sw ? om2 : m2, lm1);
    hi = sw ? ohi : hi;
    lo = sw ? olo : lo;
}

// Wave-level top-2: ror 1,2,4,8 = exact ring over each row of 16 (each lane
// merged exactly once -> top-2 monoid exact); bcast15 then bcast31 funnel
// rows into lane 63 (R6-validated control codes; lane 63's value is the
// exact wave top-2 -- self-merge corruption on untargeted rows is unused).
__device__ __forceinline__ void wave_post_top2(FpsSmem& sm, int p, int wave, int lane,
                                               float m1, float m2, int g1) {
    unsigned hi = __float_as_uint(m1);
    unsigned lo = ~(unsigned)g1;
    top2_step<0x121>(hi, lo, m2);  // row_ror:1
    top2_step<0x122>(hi, lo, m2);  // row_ror:2
    top2_step<0x124>(hi, lo, m2);  // row_ror:4
    top2_step<0x128>(hi, lo, m2);  // row_ror:8
    top2_step<0x142>(hi, lo, m2);  // row_bcast15
    top2_step<0x143>(hi, lo, m2);  // row_bcast31
    if (lane == 63) {
        sm.skey[p][wave] = ((unsigned long long)hi << 32) | (unsigned long long)lo;
        sm.sm2v[p][wave] = m2;
    }
}

// ---------------------------------------------------------------------------
// FPS, single stage (prefix property, R4-validated), ONE barrier per
// iteration. Inner-loop numerics = R0-R4-validated fp32 top-2 form.
// Selection total order identical to validated atomicMax. Cert: M2 >= thr
// (R1/R2-validated equivalence). fp64 fallback verbatim.
// ---------------------------------------------------------------------------
__device__ __forceinline__ void fps_run(FpsSmem& sm, const float* __restrict__ pts,
                                        int n_out, int* __restrict__ fi) {
    constexpr int T = 1024;
    constexpr int P = 16;
    constexpr int NW = T / 64;
    const int tid = threadIdx.x;
    const int wave = tid >> 6, lane = tid & 63;

    float xr[P], yr[P], zr[P], c[P];
    const float sx0 = pts[0], sy0 = pts[1], sz0 = pts[2];
    if (tid == 0) fi[0] = 0;

    // prologue: coords -> LDS (x,y) + registers (all), update vs sample 0,
    // per-thread top-2, wave top-2, post into parity-1 slots.
    float m1 = -1.0f, m2 = -1.0f;
    int g1 = 0x7fffffff;
#pragma unroll
    for (int q = 0; q < P; ++q) {
        const int g = tid + q * T;
        const float x = pts[g * 3 + 0];
        const float y = pts[g * 3 + 1];
        const float z = pts[g * 3 + 2];
        sm.sx[g] = x;
        sm.sy[g] = y;
        xr[q] = x; yr[q] = y; zr[q] = z;
        const float dx = x - sx0, dy = y - sy0, dz = z - sz0;
        const float t = fmaf(dx, dx, fmaf(dy, dy, dz * dz));
        const float nc = fminf(FLT_MAX, t);
        c[q] = nc;
        const bool gt = nc > m1;
        m2 = fmaxf(m2, fminf(nc, m1));
        m1 = fmaxf(m1, nc);
        g1 = gt ? g : g1;
    }
    wave_post_top2(sm, 1, wave, lane, m1, m2, g1);

    for (int s = 1; s < n_out; ++s) {
        __syncthreads();  // THE barrier: prev interval's posts (parity s&1) visible
        const int par = s & 1;

        // cross-slot top-2 (all lanes converge to identical M1, G1, M2)
        unsigned hi, lo;
        float M2v;
        {
            const unsigned long long k0 = sm.skey[par][lane & 15];
            M2v = sm.sm2v[par][lane & 15];
            hi = (unsigned)(k0 >> 32);
            lo = (unsigned)k0;
            top2_step<0x121>(hi, lo, M2v);  // ring over the 16 slots
            top2_step<0x122>(hi, lo, M2v);
            top2_step<0x124>(hi, lo, M2v);
            top2_step<0x128>(hi, lo, M2v);
        }
        const float M1 = __uint_as_float(hi);
        const int G1 = (int)(~lo);
        const float thr = M1 - M1 * CERT_EPS;

        // winner coords: broadcast LDS reads (x,y) + one uniform global (z)
        float nx = sm.sx[G1];
        float ny = sm.sy[G1];
        float nz = pts[G1 * 3 + 2];
        int wg = G1;

        if (M2v >= thr) {
            // ---- cooperative exact fp64 fallback (uniform branch, verbatim) ----
            unsigned miss = 0;
#pragma unroll
            for (int q = 0; q < P; ++q)
                if (c[q] >= thr) miss |= (1u << q);
            double BD = -1.0;
            int BG = 0x7fffffff;
            for (;;) {
                if (tid == 0) { sm.cand_cnt = 0; sm.more_flag = 0; }
                __syncthreads();
#pragma unroll
                for (int q = 0; q < P; ++q) {
                    if (miss & (1u << q)) {
                        int slot = atomicAdd(&sm.cand_cnt, 1);
                        if (slot < 64) {
                            sm.cand_idx[slot] = tid + q * T;
                            miss &= ~(1u << q);
                        } else {
                            sm.more_flag = 1;
                        }
                    }
                }
                __syncthreads();
                int ncand = sm.cand_cnt;
                if (ncand > 64) ncand = 64;
                for (int ci = 0; ci < ncand; ++ci) {
                    const int g = sm.cand_idx[ci];
                    const double qx = (double)pts[g * 3 + 0];
                    const double qy = (double)pts[g * 3 + 1];
                    const double qz = (double)pts[g * 3 + 2];
                    double dmin = DBL_MAX;
                    for (int i = tid; i < s; i += T) {
                        const int h = fi[i];
                        double ddx = qx - (double)pts[h * 3 + 0];
                        double ddy = qy - (double)pts[h * 3 + 1];
                        double ddz = qz - (double)pts[h * 3 + 2];
                        double dd = ddx * ddx + ddy * ddy + ddz * ddz;
                        dmin = (dd < dmin) ? dd : dmin;
                    }
                    for (int off = 32; off; off >>= 1) {
                        double od = __shfl_xor(dmin, off);
                        dmin = (od < dmin) ? od : dmin;
                    }
                    if (lane == 0) sm.red_d[wave] = dmin;
                    __syncthreads();
                    double dall = sm.red_d[0];
#pragma unroll
                    for (int w = 1; w < NW; ++w) dall = (sm.red_d[w] < dall) ? sm.red_d[w] : dall;
                    if (dall > BD || (dall == BD && g < BG)) { BD = dall; BG = g; }
                    __syncthreads();
                }
                int mf = sm.more_flag;
                __syncthreads();
                if (!mf) break;
            }
            wg = BG;
            nx = pts[wg * 3 + 0];
            ny = pts[wg * 3 + 1];
            nz = pts[wg * 3 + 2];
        }

        if (tid == 0) fi[s] = wg;
        if (s == n_out - 1) break;

        // fused min-update + per-thread top-2 (R0-R4-validated numerics)
        float nm1 = -1.0f, nm2 = -1.0f;
        int ng1 = 0x7fffffff;
#pragma unroll
        for (int q = 0; q < P; ++q) {
            const float dx = xr[q] - nx, dy = yr[q] - ny, dz = zr[q] - nz;
            const float t = fmaf(dx, dx, fmaf(dy, dy, dz * dz));
            const float nc = fminf(c[q], t);
            c[q] = nc;
            const bool gt = nc > nm1;
            nm2 = fmaxf(nm2, fminf(nc, nm1));
            nm1 = fmaxf(nm1, nc);
            ng1 = gt ? (tid + q * T) : ng1;
        }
        m1 = nm1; m2 = nm2; g1 = ng1;
        wave_post_top2(sm, par ^ 1, wave, lane, m1, m2, g1);
    }
}

// ---------------------------------------------------------------------------
// Fused KNN + EdgeConv body: 1024 threads = 16 waves = 16 query points.
// Per-wave fp64-exact top-16 (verbatim). EdgeConv h2 via per-wave LDS h1
// staging + broadcast float4 reads (R6-R9 validated, bit-identical order).
// ---------------------------------------------------------------------------
struct KnnSmem {
    float sx[KNN_TILE], sy[KNN_TILE], sz[KNN_TILE];
    float w1[6 * 64], b1v[64], w2[64 * 64], b2v[64];
    __align__(16) float h1buf[16][64];
};

__device__ __forceinline__ void knn_edge_body(
    KnnSmem& sm, const float* __restrict__ pts,
    const float* __restrict__ ew1, const float* __restrict__ eb1,
    const float* __restrict__ ew2, const float* __restrict__ eb2,
    float* __restrict__ feats, int qb) {
    for (int t = threadIdx.x; t < 6 * 64; t += 1024) sm.w1[t] = ew1[t];
    for (int t = threadIdx.x; t < 64; t += 1024) { sm.b1v[t] = eb1[t]; sm.b2v[t] = eb2[t]; }
    for (int t = threadIdx.x; t < 64 * 64; t += 1024) sm.w2[t] = ew2[t];

    const int wave = threadIdx.x >> 6;
    const int lane = threadIdx.x & 63;
    const int qi = qb * 16 + wave;
    const double qxd = (double)pts[qi * 3 + 0];
    const double qyd = (double)pts[qi * 3 + 1];
    const double qzd = (double)pts[qi * 3 + 2];

    double ld[16];
    int li[16];
#pragma unroll
    for (int s = 0; s < 16; ++s) { ld[s] = DBL_MAX; li[s] = 0x7fffffff; }
    double md = DBL_MAX; int mj = 0x7fffffff; int mslot = 0;

    for (int t0 = 0; t0 < N_PTS; t0 += KNN_TILE) {
        __syncthreads();
        for (int t = threadIdx.x; t < KNN_TILE; t += 1024) {
            sm.sx[t] = pts[(t0 + t) * 3 + 0];
            sm.sy[t] = pts[(t0 + t) * 3 + 1];
            sm.sz[t] = pts[(t0 + t) * 3 + 2];
        }
        __syncthreads();
#pragma unroll
        for (int m = 0; m < KNN_TILE / 64; ++m) {
            const int cc = lane + m * 64;
            const int j = t0 + cc;
            if (j == qi) continue;  // diagonal excluded (d=inf in reference)
            double dx = qxd - (double)sm.sx[cc];
            double dy = qyd - (double)sm.sy[cc];
            double dz = qzd - (double)sm.sz[cc];
            double dd = dx * dx + dy * dy + dz * dz;
            if (dd < md || (dd == md && j < mj)) {
#pragma unroll
                for (int s = 0; s < 16; ++s)
                    if (s == mslot) { ld[s] = dd; li[s] = j; }
                md = -1.0; mj = -1; mslot = 0;
#pragma unroll
                for (int s = 0; s < 16; ++s) {
                    bool g = (ld[s] > md) || (ld[s] == md && li[s] > mj);
                    if (g) { md = ld[s]; mj = li[s]; mslot = s; }
                }
            }
        }
    }

    const float xi = pts[qi * 3], yi = pts[qi * 3 + 1], zi = pts[qi * 3 + 2];
    float acc = -FLT_MAX;
    for (int r = 0; r < KNN_K; ++r) {
        double cd = DBL_MAX; int cj = 0x7fffffff; int cs = 0;
#pragma unroll
        for (int s = 0; s < 16; ++s) {
            bool l = (ld[s] < cd) || (ld[s] == cd && li[s] < cj);
            if (l) { cd = ld[s]; cj = li[s]; cs = s; }
        }
        double wd = cd; int wj = cj;
        for (int off = 32; off; off >>= 1) {
            double od = __shfl_xor(wd, off);
            int oj = __shfl_xor(wj, off);
            if (od < wd || (od == wd && oj < wj)) { wd = od; wj = oj; }
        }
        if (cd == wd && cj == wj) {
#pragma unroll
            for (int s = 0; s < 16; ++s)
                if (s == cs) { ld[s] = DBL_MAX; li[s] = 0x7fffffff; }
        }
        const float xj = pts[wj * 3], yj = pts[wj * 3 + 1], zj = pts[wj * 3 + 2];
        const float f3 = xj - xi, f4 = yj - yi, f5 = zj - zi;
        float h1 = sm.b1v[lane];
        h1 = fmaf(xi, sm.w1[0 * 64 + lane], h1);
        h1 = fmaf(yi, sm.w1[1 * 64 + lane], h1);
        h1 = fmaf(zi, sm.w1[2 * 64 + lane], h1);
        h1 = fmaf(f3, sm.w1[3 * 64 + lane], h1);
        h1 = fmaf(f4, sm.w1[4 * 64 + lane], h1);
        h1 = fmaf(f5, sm.w1[5 * 64 + lane], h1);
        h1 = fmaxf(h1, 0.0f);
        sm.h1buf[wave][lane] = h1;
        float h2 = sm.b2v[lane];
        const float4* h4 = reinterpret_cast<const float4*>(&sm.h1buf[wave][0]);
#pragma unroll
        for (int dd = 0; dd < 16; ++dd) {
            const float4 hv = h4[dd];
            h2 = fmaf(hv.x, sm.w2[(dd * 4 + 0) * 64 + lane], h2);
            h2 = fmaf(hv.y, sm.w2[(dd * 4 + 1) * 64 + lane], h2);
            h2 = fmaf(hv.z, sm.w2[(dd * 4 + 2) * 64 + lane], h2);
            h2 = fmaf(hv.w, sm.w2[(dd * 4 + 3) * 64 + lane], h2);
        }
        acc = fmaxf(acc, h2);
    }
    feats[qi * 64 + lane] = acc;
}

// ---------------------------------------------------------------------------
// Mega kernel: block 0 = single FPS stage (prefix property: fi1/fi2 are
// prefixes of fi0) + sp writeback. Blocks 1..1024 = fused knn+edgeconv.
// Union LDS ~129 KB -> KNN at 1 block/CU (measured slack covers it).
// ---------------------------------------------------------------------------
__global__ __launch_bounds__(1024)
void mega_kernel(const float* __restrict__ pts,
                 const float* __restrict__ ew1, const float* __restrict__ eb1,
                 const float* __restrict__ ew2, const float* __restrict__ eb2,
                 float* __restrict__ feats,
                 int* __restrict__ fi0,
                 float* __restrict__ sp0, float* __restrict__ sp1,
                 float* __restrict__ sp2) {
    constexpr size_t SMEM_BYTES =
        sizeof(FpsSmem) > sizeof(KnnSmem) ? sizeof(FpsSmem) : sizeof(KnnSmem);
    __shared__ __align__(16) char raw[SMEM_BYTES];
    if (blockIdx.x == 0) {
        FpsSmem& sm = *reinterpret_cast<FpsSmem*>(raw);
        fps_run(sm, pts, 4096, fi0);
        __syncthreads();
        const int tid = threadIdx.x;
        for (int t = tid; t < 4096; t += 1024) {
            const int g = fi0[t];
            const float x = pts[g * 3 + 0];
            const float y = pts[g * 3 + 1];
            const float z = pts[g * 3 + 2];
            sp0[t * 3 + 0] = x;
            sp0[t * 3 + 1] = y;
            sp0[t * 3 + 2] = z;
            if (t < 1024) {
                sp1[t * 3 + 0] = x;
                sp1[t * 3 + 1] = y;
                sp1[t * 3 + 2] = z;
            }
            if (t < 256) {
                sp2[t * 3 + 0] = x;
                sp2[t * 3 + 1] = y;
                sp2[t * 3 + 2] = z;
            }
        }
    } else {
        knn_edge_body(*reinterpret_cast<KnnSmem*>(raw), pts, ew1, eb1, ew2, eb2,
                      feats, blockIdx.x - 1);
    }
}

// ---------------------------------------------------------------------------
// Tail: all three MLPs in one launch (validated mlp numerics, verbatim).
// All stages index feats via fi0 prefixes (prefix property).
// ---------------------------------------------------------------------------
__device__ __forceinline__ void mlp_body(
    const float* __restrict__ feats, const int* __restrict__ orig,
    const float* __restrict__ mw1, const float* __restrict__ mb1,
    const float* __restrict__ mw2, const float* __restrict__ mb2,
    float* __restrict__ outp, int pb) {
    __shared__ float sfl[64], h1l[128];
    const int t = threadIdx.x;
    for (int pl = 0; pl < 16; ++pl) {
        const int p = pb * 16 + pl;
        const int g = orig[p];
        if (t < 64) sfl[t] = feats[g * 64 + t];
        __syncthreads();
        if (t < 128) {
            float h = mb1[t];
            for (int dd = 0; dd < 64; ++dd)
                h = fmaf(sfl[dd], mw1[dd * 128 + t], h);
            h1l[t] = fmaxf(h, 0.0f);
        }
        __syncthreads();
        float o = mb2[t];
        for (int dd = 0; dd < 128; ++dd)
            o = fmaf(h1l[dd], mw2[dd * 256 + t], o);
        outp[p * 256 + t] = o;
        __syncthreads();
    }
}

__global__ __launch_bounds__(256) void tail_kernel(
    const float* __restrict__ feats,
    const int* __restrict__ fi0,
    const float* __restrict__ mw1, const float* __restrict__ mb1,
    const float* __restrict__ mw2, const float* __restrict__ mb2,
    float* __restrict__ out) {
    const int b = blockIdx.x;
    float* lf0 = out + 12288;
    float* lf1 = out + 1063936;
    float* lf2 = out + 1326848;
    if (b < 256) {
        mlp_body(feats, fi0, mw1 + 0 * 8192, mb1 + 0 * 128,
                 mw2 + 0 * 32768, mb2 + 0 * 256, lf0, b);
    } else if (b < 320) {
        mlp_body(feats, fi0, mw1 + 1 * 8192, mb1 + 1 * 128,
                 mw2 + 1 * 32768, mb2 + 1 * 256, lf1, b - 256);
    } else {
        mlp_body(feats, fi0, mw1 + 2 * 8192, mb1 + 2 * 128,
                 mw2 + 2 * 32768, mb2 + 2 * 256, lf2, b - 320);
    }
}

// ---------------------------------------------------------------------------
extern "C" void kernel_launch(void* const* d_in, const int* in_sizes, int n_in,
                              void* d_out, int out_size, void* d_ws, size_t ws_size,
                              hipStream_t stream) {
    const float* pts = (const float*)d_in[0];
    const float* ew1 = (const float*)d_in[1];
    const float* eb1 = (const float*)d_in[2];
    const float* ew2 = (const float*)d_in[3];
    const float* eb2 = (const float*)d_in[4];
    const float* mw1 = (const float*)d_in[5];  // (3,64,128)
    const float* mb1 = (const float*)d_in[6];  // (3,128)
    const float* mw2 = (const float*)d_in[7];  // (3,128,256)
    const float* mb2 = (const float*)d_in[8];  // (3,256)
    float* out = (float*)d_out;
    char* ws = (char*)d_ws;

    float* feats = (float*)(ws + 0);           // 16384*64*4 = 4 MB
    int* fi0 = (int*)(ws + 4194304);           // 4096 ints (original indices)

    float* sp0 = out + 0;
    float* sp1 = out + 1060864;
    float* sp2 = out + 1326080;

    mega_kernel<<<1 + N_PTS / 16, 1024, 0, stream>>>(pts, ew1, eb1, ew2, eb2, feats,
                                                     fi0, sp0, sp1, sp2);
    tail_kernel<<<336, 256, 0, stream>>>(feats, fi0, mw1, mb1, mw2, mb2, out);
}

// Round 11
// 6824.967 us; speedup vs baseline: 1.4292x; 1.4292x over previous
//
#include <hip/hip_runtime.h>
#include <cfloat>
#include <cstdint>

#define N_PTS 16384
#define KNN_K 16
#define KNN_TILE 512
#define CERT_EPS 3e-6f

// ---------------------------------------------------------------------------
// FPS shared block -- R5 VERBATIM (best measured: 6845 us total / 6750 us
// steady). ALL coordinates (x,y,z) in per-thread registers; LDS holds only
// the reduction slots (~1 KB): packed-key atomicMax spread over 16 slots,
// parity double-buffered.
// ---------------------------------------------------------------------------
struct FpsSmem {
    unsigned long long slots[2][16]; // packed (m1,~g), tid&15-spread, parity dbuf
    int cw2[2][2];                   // [par][0]=#threads m1>=thr, [1]=winner m2>=thr
    float4 pub;                      // winner xyz, owner-published each iter
    int cand_idx[64];
    int cand_cnt;
    int more_flag;
    double red_d[16];
};

// DPP move (VALU pipe -- no DS). old=v keeps non-targeted lanes unchanged.
template <int CTRL>
__device__ __forceinline__ unsigned dpp_mov_u32(unsigned v) {
    return (unsigned)__builtin_amdgcn_update_dpp((int)v, (int)v, CTRL, 0xF, 0xF, false);
}

// Cross-slot max over the 16 slot keys, entirely on the VALU pipe (validated
// rounds 3-5). u64 numeric compare == atomicMax total order (larger m1,
// tie -> smaller g). Every lane converges to the global (M1, G1).
__device__ __forceinline__ void cross_slot_reduce(unsigned long long k, float& M1, int& G1) {
    unsigned hi = (unsigned)(k >> 32), lo = (unsigned)k;
#define RSTEP(CTRL)                                          \
    {                                                        \
        const unsigned ohi = dpp_mov_u32<CTRL>(hi);          \
        const unsigned olo = dpp_mov_u32<CTRL>(lo);          \
        const bool b = (ohi > hi) || (ohi == hi && olo > lo);\
        hi = b ? ohi : hi;                                   \
        lo = b ? olo : lo;                                   \
    }
    RSTEP(0x121)  // row_ror:1
    RSTEP(0x122)  // row_ror:2
    RSTEP(0x124)  // row_ror:4
    RSTEP(0x128)  // row_ror:8
#undef RSTEP
    M1 = __uint_as_float(hi);
    G1 = (int)(~lo);
}

// ---------------------------------------------------------------------------
// FPS, single stage (4096 samples; stages 1/2 are exact prefixes -- round-4
// validated). R5 verbatim: distance-update numerics fp32 fmaf form;
// selection total order identical to validated atomicMax; cert: fallback iff
// (#threads m1>=thr)>1 || winner_m2>=thr, winner_m2 recomputed exactly by
// the unique owner as max_{q != qw} c[q]. fp64 fallback verbatim.
// ---------------------------------------------------------------------------
__device__ __forceinline__ void fps_run(FpsSmem& sm, const float* __restrict__ pts,
                                        int n_out, int* __restrict__ fi) {
    constexpr int T = 1024;
    constexpr int P = 16;
    constexpr int NW = T / 64;
    const int tid = threadIdx.x;
    const int wave = tid >> 6, lane = tid & 63;

    if (tid < 32) sm.slots[tid >> 4][tid & 15] = 0ull;
    if (tid < 4) sm.cw2[tid >> 1][tid & 1] = 0;

    float xr[P], yr[P], zr[P], c[P];
    const float sx0 = pts[0], sy0 = pts[1], sz0 = pts[2];
    if (tid == 0) fi[0] = 0;

    // prologue: load coords into registers, update vs sample 0
    float m1 = -1.0f;
    int g1 = 0x7fffffff;
#pragma unroll
    for (int q = 0; q < P; ++q) {
        const int g = tid + q * T;
        const float x = pts[g * 3 + 0];
        const float y = pts[g * 3 + 1];
        const float z = pts[g * 3 + 2];
        xr[q] = x;
        yr[q] = y;
        zr[q] = z;
        const float dx = x - sx0, dy = y - sy0, dz = z - sz0;
        const float t = fmaf(dx, dx, fmaf(dy, dy, dz * dz));
        const float nc = fminf(FLT_MAX, t);
        c[q] = nc;
        const bool gt = nc > m1;
        m1 = fmaxf(m1, nc);
        g1 = gt ? g : g1;
    }
    __syncthreads();  // slot/cw2 init visible before first posts
    {
        const unsigned long long key =
            ((unsigned long long)__float_as_uint(m1) << 32) |
            (unsigned long long)(~(unsigned)g1);
        atomicMax(&sm.slots[1][tid & 15], key);
    }

    for (int s = 1; s < n_out; ++s) {
        __syncthreads();  // barrier A: slot posts of this parity visible
        const int par = s & 1;

        const unsigned long long k0 = sm.slots[par][lane & 15];
        float M1;
        int G1;
        cross_slot_reduce(k0, M1, G1);
        const float thr = M1 - M1 * CERT_EPS;

        // owner publication + winner-m2 cert post: the unique owner thread
        // of the winning point posts xyz (all from registers) and its exact
        // second max over its own c[] (excluding the argmax slot qw).
        if (g1 == G1) {
            const int qw = (G1 - tid) >> 10;  // /1024
            float xw = 0.0f, yw = 0.0f, zw = 0.0f, m2w = -1.0f;
#pragma unroll
            for (int q = 0; q < P; ++q) {
                if (q == qw) { xw = xr[q]; yw = yr[q]; zw = zr[q]; }
                else m2w = fmaxf(m2w, c[q]);
            }
            sm.pub = make_float4(xw, yw, zw, 0.0f);
            sm.cw2[par][1] = (m2w >= thr) ? 1 : 0;
        }

        // resets for the next iteration's parity (race-free: next parity's
        // posts happen only after barrier B)
        if (tid < 16) sm.slots[par ^ 1][tid] = 0ull;
        if (tid == 0) { sm.cw2[par ^ 1][0] = 0; sm.cw2[par ^ 1][1] = 0; }

        // cert count (validated): #threads with m1>=thr via per-wave ballot
        // + one atomicAdd per wave.
        const unsigned long long bal = __ballot(m1 >= thr);
        if (lane == 0) atomicAdd(&sm.cw2[par][0], (int)__popcll(bal));

        __syncthreads();  // barrier B: pub + cert posts visible
        const int2 tw = *reinterpret_cast<const int2*>(&sm.cw2[par][0]);
        const int total = tw.x, wfl = tw.y;
        const float4 wc = sm.pub;
        float nx = wc.x, ny = wc.y, nz = wc.z;
        int wg = G1;

        if (total > 1 || wfl) {
            // ---- cooperative exact fp64 fallback (uniform branch, verbatim) ----
            unsigned miss = 0;
#pragma unroll
            for (int q = 0; q < P; ++q)
                if (c[q] >= thr) miss |= (1u << q);
            double BD = -1.0;
            int BG = 0x7fffffff;
            for (;;) {
                if (tid == 0) { sm.cand_cnt = 0; sm.more_flag = 0; }
                __syncthreads();
#pragma unroll
                for (int q = 0; q < P; ++q) {
                    if (miss & (1u << q)) {
                        int slot = atomicAdd(&sm.cand_cnt, 1);
                        if (slot < 64) {
                            sm.cand_idx[slot] = tid + q * T;
                            miss &= ~(1u << q);
                        } else {
                            sm.more_flag = 1;
                        }
                    }
                }
                __syncthreads();
                int ncand = sm.cand_cnt;
                if (ncand > 64) ncand = 64;
                for (int ci = 0; ci < ncand; ++ci) {
                    const int g = sm.cand_idx[ci];
                    const double qx = (double)pts[g * 3 + 0];
                    const double qy = (double)pts[g * 3 + 1];
                    const double qz = (double)pts[g * 3 + 2];
                    double dmin = DBL_MAX;
                    for (int i = tid; i < s; i += T) {
                        const int h = fi[i];
                        double ddx = qx - (double)pts[h * 3 + 0];
                        double ddy = qy - (double)pts[h * 3 + 1];
                        double ddz = qz - (double)pts[h * 3 + 2];
                        double dd = ddx * ddx + ddy * ddy + ddz * ddz;
                        dmin = (dd < dmin) ? dd : dmin;
                    }
                    for (int off = 32; off; off >>= 1) {
                        double od = __shfl_xor(dmin, off);
                        dmin = (od < dmin) ? od : dmin;
                    }
                    if (lane == 0) sm.red_d[wave] = dmin;
                    __syncthreads();
                    double dall = sm.red_d[0];
#pragma unroll
                    for (int w = 1; w < NW; ++w) dall = (sm.red_d[w] < dall) ? sm.red_d[w] : dall;
                    if (dall > BD || (dall == BD && g < BG)) { BD = dall; BG = g; }
                    __syncthreads();
                }
                int mf = sm.more_flag;
                __syncthreads();
                if (!mf) break;
            }
            wg = BG;
            nx = pts[wg * 3 + 0];
            ny = pts[wg * 3 + 1];
            nz = pts[wg * 3 + 2];
        }

        if (tid == 0) fi[s] = wg;
        if (s == n_out - 1) break;

        // fused min-update + per-thread argmax (validated numerics; winner
        // m2 recomputed exactly by the owner above).
        float nm1 = -1.0f;
        int ng1 = 0x7fffffff;
#pragma unroll
        for (int q = 0; q < P; ++q) {
            const float dx = xr[q] - nx, dy = yr[q] - ny, dz = zr[q] - nz;
            const float t = fmaf(dx, dx, fmaf(dy, dy, dz * dz));
            const float nc = fminf(c[q], t);
            c[q] = nc;
            const bool gt = nc > nm1;
            nm1 = fmaxf(nm1, nc);
            ng1 = gt ? (tid + q * T) : ng1;
        }
        m1 = nm1; g1 = ng1;
        const unsigned long long key =
            ((unsigned long long)__float_as_uint(m1) << 32) |
            (unsigned long long)(~(unsigned)g1);
        atomicMax(&sm.slots[par ^ 1][tid & 15], key);
    }
}

// ---------------------------------------------------------------------------
// Fused KNN + EdgeConv body: 1024 threads = 16 waves = 16 query points.
// Per-wave fp64-exact top-16 (verbatim). EdgeConv h2 via per-wave LDS h1
// staging + broadcast float4 reads (R6-R10 validated, bit-identical fmaf
// order) -- ~4x fewer DS ops than the __shfl form, reducing DS-pipe
// contention with the FPS block sharing the CU.
// ---------------------------------------------------------------------------
struct KnnSmem {
    float sx[KNN_TILE], sy[KNN_TILE], sz[KNN_TILE];
    float w1[6 * 64], b1v[64], w2[64 * 64], b2v[64];
    __align__(16) float h1buf[16][64];
};

__device__ __forceinline__ void knn_edge_body(
    KnnSmem& sm, const float* __restrict__ pts,
    const float* __restrict__ ew1, const float* __restrict__ eb1,
    const float* __restrict__ ew2, const float* __restrict__ eb2,
    float* __restrict__ feats, int qb) {
    for (int t = threadIdx.x; t < 6 * 64; t += 1024) sm.w1[t] = ew1[t];
    for (int t = threadIdx.x; t < 64; t += 1024) { sm.b1v[t] = eb1[t]; sm.b2v[t] = eb2[t]; }
    for (int t = threadIdx.x; t < 64 * 64; t += 1024) sm.w2[t] = ew2[t];

    const int wave = threadIdx.x >> 6;
    const int lane = threadIdx.x & 63;
    const int qi = qb * 16 + wave;
    const double qxd = (double)pts[qi * 3 + 0];
    const double qyd = (double)pts[qi * 3 + 1];
    const double qzd = (double)pts[qi * 3 + 2];

    double ld[16];
    int li[16];
#pragma unroll
    for (int s = 0; s < 16; ++s) { ld[s] = DBL_MAX; li[s] = 0x7fffffff; }
    double md = DBL_MAX; int mj = 0x7fffffff; int mslot = 0;

    for (int t0 = 0; t0 < N_PTS; t0 += KNN_TILE) {
        __syncthreads();
        for (int t = threadIdx.x; t < KNN_TILE; t += 1024) {
            sm.sx[t] = pts[(t0 + t) * 3 + 0];
            sm.sy[t] = pts[(t0 + t) * 3 + 1];
            sm.sz[t] = pts[(t0 + t) * 3 + 2];
        }
        __syncthreads();
#pragma unroll
        for (int m = 0; m < KNN_TILE / 64; ++m) {
            const int cc = lane + m * 64;
            const int j = t0 + cc;
            if (j == qi) continue;  // diagonal excluded (d=inf in reference)
            double dx = qxd - (double)sm.sx[cc];
            double dy = qyd - (double)sm.sy[cc];
            double dz = qzd - (double)sm.sz[cc];
            double dd = dx * dx + dy * dy + dz * dz;
            if (dd < md || (dd == md && j < mj)) {
#pragma unroll
                for (int s = 0; s < 16; ++s)
                    if (s == mslot) { ld[s] = dd; li[s] = j; }
                md = -1.0; mj = -1; mslot = 0;
#pragma unroll
                for (int s = 0; s < 16; ++s) {
                    bool g = (ld[s] > md) || (ld[s] == md && li[s] > mj);
                    if (g) { md = ld[s]; mj = li[s]; mslot = s; }
                }
            }
        }
    }

    const float xi = pts[qi * 3], yi = pts[qi * 3 + 1], zi = pts[qi * 3 + 2];
    float acc = -FLT_MAX;
    for (int r = 0; r < KNN_K; ++r) {
        double cd = DBL_MAX; int cj = 0x7fffffff; int cs = 0;
#pragma unroll
        for (int s = 0; s < 16; ++s) {
            bool l = (ld[s] < cd) || (ld[s] == cd && li[s] < cj);
            if (l) { cd = ld[s]; cj = li[s]; cs = s; }
        }
        double wd = cd; int wj = cj;
        for (int off = 32; off; off >>= 1) {
            double od = __shfl_xor(wd, off);
            int oj = __shfl_xor(wj, off);
            if (od < wd || (od == wd && oj < wj)) { wd = od; wj = oj; }
        }
        if (cd == wd && cj == wj) {
#pragma unroll
            for (int s = 0; s < 16; ++s)
                if (s == cs) { ld[s] = DBL_MAX; li[s] = 0x7fffffff; }
        }
        const float xj = pts[wj * 3], yj = pts[wj * 3 + 1], zj = pts[wj * 3 + 2];
        const float f3 = xj - xi, f4 = yj - yi, f5 = zj - zi;
        float h1 = sm.b1v[lane];
        h1 = fmaf(xi, sm.w1[0 * 64 + lane], h1);
        h1 = fmaf(yi, sm.w1[1 * 64 + lane], h1);
        h1 = fmaf(zi, sm.w1[2 * 64 + lane], h1);
        h1 = fmaf(f3, sm.w1[3 * 64 + lane], h1);
        h1 = fmaf(f4, sm.w1[4 * 64 + lane], h1);
        h1 = fmaf(f5, sm.w1[5 * 64 + lane], h1);
        h1 = fmaxf(h1, 0.0f);
        // stage h1 to this wave's LDS row; read back broadcast float4.
        // fmaf order d = 0..63 preserved -> bit-identical to __shfl version.
        sm.h1buf[wave][lane] = h1;
        float h2 = sm.b2v[lane];
        const float4* h4 = reinterpret_cast<const float4*>(&sm.h1buf[wave][0]);
#pragma unroll
        for (int dd = 0; dd < 16; ++dd) {
            const float4 hv = h4[dd];
            h2 = fmaf(hv.x, sm.w2[(dd * 4 + 0) * 64 + lane], h2);
            h2 = fmaf(hv.y, sm.w2[(dd * 4 + 1) * 64 + lane], h2);
            h2 = fmaf(hv.z, sm.w2[(dd * 4 + 2) * 64 + lane], h2);
            h2 = fmaf(hv.w, sm.w2[(dd * 4 + 3) * 64 + lane], h2);
        }
        acc = fmaxf(acc, h2);
    }
    feats[qi * 64 + lane] = acc;
}

// ---------------------------------------------------------------------------
// Mega kernel: block 0 = single FPS stage (prefix property: fi1/fi2 are
// prefixes of fi0) + sp writeback. Blocks 1..1024 = fused knn+edgeconv,
// hidden under fps. Union LDS ~28 KB -> 2 blocks/CU.
// ---------------------------------------------------------------------------
__global__ __launch_bounds__(1024)
void mega_kernel(const float* __restrict__ pts,
                 const float* __restrict__ ew1, const float* __restrict__ eb1,
                 const float* __restrict__ ew2, const float* __restrict__ eb2,
                 float* __restrict__ feats,
                 int* __restrict__ fi0,
                 float* __restrict__ sp0, float* __restrict__ sp1,
                 float* __restrict__ sp2) {
    constexpr size_t SMEM_BYTES =
        sizeof(FpsSmem) > sizeof(KnnSmem) ? sizeof(FpsSmem) : sizeof(KnnSmem);
    __shared__ __align__(16) char raw[SMEM_BYTES];
    if (blockIdx.x == 0) {
        FpsSmem& sm = *reinterpret_cast<FpsSmem*>(raw);
        fps_run(sm, pts, 4096, fi0);
        __syncthreads();
        const int tid = threadIdx.x;
        for (int t = tid; t < 4096; t += 1024) {
            const int g = fi0[t];
            const float x = pts[g * 3 + 0];
            const float y = pts[g * 3 + 1];
            const float z = pts[g * 3 + 2];
            sp0[t * 3 + 0] = x;
            sp0[t * 3 + 1] = y;
            sp0[t * 3 + 2] = z;
            if (t < 1024) {
                sp1[t * 3 + 0] = x;
                sp1[t * 3 + 1] = y;
                sp1[t * 3 + 2] = z;
            }
            if (t < 256) {
                sp2[t * 3 + 0] = x;
                sp2[t * 3 + 1] = y;
                sp2[t * 3 + 2] = z;
            }
        }
    } else {
        knn_edge_body(*reinterpret_cast<KnnSmem*>(raw), pts, ew1, eb1, ew2, eb2,
                      feats, blockIdx.x - 1);
    }
}

// ---------------------------------------------------------------------------
// Tail: all three MLPs in one launch (validated mlp numerics, verbatim).
// All stages index feats via fi0 prefixes (prefix property).
// ---------------------------------------------------------------------------
__device__ __forceinline__ void mlp_body(
    const float* __restrict__ feats, const int* __restrict__ orig,
    const float* __restrict__ mw1, const float* __restrict__ mb1,
    const float* __restrict__ mw2, const float* __restrict__ mb2,
    float* __restrict__ outp, int pb) {
    __shared__ float sfl[64], h1l[128];
    const int t = threadIdx.x;
    for (int pl = 0; pl < 16; ++pl) {
        const int p = pb * 16 + pl;
        const int g = orig[p];
        if (t < 64) sfl[t] = feats[g * 64 + t];
        __syncthreads();
        if (t < 128) {
            float h = mb1[t];
            for (int dd = 0; dd < 64; ++dd)
                h = fmaf(sfl[dd], mw1[dd * 128 + t], h);
            h1l[t] = fmaxf(h, 0.0f);
        }
        __syncthreads();
        float o = mb2[t];
        for (int dd = 0; dd < 128; ++dd)
            o = fmaf(h1l[dd], mw2[dd * 256 + t], o);
        outp[p * 256 + t] = o;
        __syncthreads();
    }
}

__global__ __launch_bounds__(256) void tail_kernel(
    const float* __restrict__ feats,
    const int* __restrict__ fi0,
    const float* __restrict__ mw1, const float* __restrict__ mb1,
    const float* __restrict__ mw2, const float* __restrict__ mb2,
    float* __restrict__ out) {
    const int b = blockIdx.x;
    float* lf0 = out + 12288;
    float* lf1 = out + 1063936;
    float* lf2 = out + 1326848;
    if (b < 256) {
        mlp_body(feats, fi0, mw1 + 0 * 8192, mb1 + 0 * 128,
                 mw2 + 0 * 32768, mb2 + 0 * 256, lf0, b);
    } else if (b < 320) {
        mlp_body(feats, fi0, mw1 + 1 * 8192, mb1 + 1 * 128,
                 mw2 + 1 * 32768, mb2 + 1 * 256, lf1, b - 256);
    } else {
        mlp_body(feats, fi0, mw1 + 2 * 8192, mb1 + 2 * 128,
                 mw2 + 2 * 32768, mb2 + 2 * 256, lf2, b - 320);
    }
}

// ---------------------------------------------------------------------------
extern "C" void kernel_launch(void* const* d_in, const int* in_sizes, int n_in,
                              void* d_out, int out_size, void* d_ws, size_t ws_size,
                              hipStream_t stream) {
    const float* pts = (const float*)d_in[0];
    const float* ew1 = (const float*)d_in[1];
    const float* eb1 = (const float*)d_in[2];
    const float* ew2 = (const float*)d_in[3];
    const float* eb2 = (const float*)d_in[4];
    const float* mw1 = (const float*)d_in[5];  // (3,64,128)
    const float* mb1 = (const float*)d_in[6];  // (3,128)
    const float* mw2 = (const float*)d_in[7];  // (3,128,256)
    const float* mb2 = (const float*)d_in[8];  // (3,256)
    float* out = (float*)d_out;
    char* ws = (char*)d_ws;

    float* feats = (float*)(ws + 0);           // 16384*64*4 = 4 MB
    int* fi0 = (int*)(ws + 4194304);           // 4096 ints (original indices)

    float* sp0 = out + 0;
    float* sp1 = out + 1060864;
    float* sp2 = out + 1326080;

    mega_kernel<<<1 + N_PTS / 16, 1024, 0, stream>>>(pts, ew1, eb1, ew2, eb2, feats,
                                                     fi0, sp0, sp1, sp2);
    tail_kernel<<<336, 256, 0, stream>>>(feats, fi0, mw1, mb1, mw2, mb2, out);
}

// Round 12
// 6783.924 us; speedup vs baseline: 1.4378x; 1.0061x over previous
//
#include <hip/hip_runtime.h>
#include <cfloat>
#include <cstdint>

#define N_PTS 16384
#define KNN_K 16
#define KNN_TILE 512
#define CERT_EPS 3e-6f

// ---------------------------------------------------------------------------
// FPS shared block -- R5 VERBATIM (best measured: 6824 us total / 6740 us
// steady with h1buf edgeconv). ALL coordinates (x,y,z) in per-thread
// registers; LDS holds only the reduction slots (~1 KB): packed-key
// atomicMax spread over 16 slots, parity double-buffered.
// ---------------------------------------------------------------------------
struct FpsSmem {
    unsigned long long slots[2][16]; // packed (m1,~g), tid&15-spread, parity dbuf
    int cw2[2][2];                   // [par][0]=#threads m1>=thr, [1]=winner m2>=thr
    float4 pub;                      // winner xyz, owner-published each iter
    int cand_idx[64];
    int cand_cnt;
    int more_flag;
    double red_d[16];
};

// DPP move (VALU pipe -- no DS). old=v keeps non-targeted lanes unchanged.
template <int CTRL>
__device__ __forceinline__ unsigned dpp_mov_u32(unsigned v) {
    return (unsigned)__builtin_amdgcn_update_dpp((int)v, (int)v, CTRL, 0xF, 0xF, false);
}

// Cross-slot max over the 16 slot keys, entirely on the VALU pipe (validated
// rounds 3-5). u64 numeric compare == atomicMax total order (larger m1,
// tie -> smaller g). Every lane converges to the global (M1, G1).
__device__ __forceinline__ void cross_slot_reduce(unsigned long long k, float& M1, int& G1) {
    unsigned hi = (unsigned)(k >> 32), lo = (unsigned)k;
#define RSTEP(CTRL)                                          \
    {                                                        \
        const unsigned ohi = dpp_mov_u32<CTRL>(hi);          \
        const unsigned olo = dpp_mov_u32<CTRL>(lo);          \
        const bool b = (ohi > hi) || (ohi == hi && olo > lo);\
        hi = b ? ohi : hi;                                   \
        lo = b ? olo : lo;                                   \
    }
    RSTEP(0x121)  // row_ror:1
    RSTEP(0x122)  // row_ror:2
    RSTEP(0x124)  // row_ror:4
    RSTEP(0x128)  // row_ror:8
#undef RSTEP
    M1 = __uint_as_float(hi);
    G1 = (int)(~lo);
}

// ---------------------------------------------------------------------------
// FPS, single stage (4096 samples; stages 1/2 are exact prefixes -- round-4
// validated). R5 verbatim: distance-update numerics fp32 fmaf form;
// selection total order identical to validated atomicMax; cert: fallback iff
// (#threads m1>=thr)>1 || winner_m2>=thr, winner_m2 recomputed exactly by
// the unique owner as max_{q != qw} c[q]. fp64 fallback verbatim.
// ---------------------------------------------------------------------------
__device__ __forceinline__ void fps_run(FpsSmem& sm, const float* __restrict__ pts,
                                        int n_out, int* __restrict__ fi) {
    constexpr int T = 1024;
    constexpr int P = 16;
    constexpr int NW = T / 64;
    const int tid = threadIdx.x;
    const int wave = tid >> 6, lane = tid & 63;

    if (tid < 32) sm.slots[tid >> 4][tid & 15] = 0ull;
    if (tid < 4) sm.cw2[tid >> 1][tid & 1] = 0;

    float xr[P], yr[P], zr[P], c[P];
    const float sx0 = pts[0], sy0 = pts[1], sz0 = pts[2];
    if (tid == 0) fi[0] = 0;

    // prologue: load coords into registers, update vs sample 0
    float m1 = -1.0f;
    int g1 = 0x7fffffff;
#pragma unroll
    for (int q = 0; q < P; ++q) {
        const int g = tid + q * T;
        const float x = pts[g * 3 + 0];
        const float y = pts[g * 3 + 1];
        const float z = pts[g * 3 + 2];
        xr[q] = x;
        yr[q] = y;
        zr[q] = z;
        const float dx = x - sx0, dy = y - sy0, dz = z - sz0;
        const float t = fmaf(dx, dx, fmaf(dy, dy, dz * dz));
        const float nc = fminf(FLT_MAX, t);
        c[q] = nc;
        const bool gt = nc > m1;
        m1 = fmaxf(m1, nc);
        g1 = gt ? g : g1;
    }
    __syncthreads();  // slot/cw2 init visible before first posts
    {
        const unsigned long long key =
            ((unsigned long long)__float_as_uint(m1) << 32) |
            (unsigned long long)(~(unsigned)g1);
        atomicMax(&sm.slots[1][tid & 15], key);
    }

    for (int s = 1; s < n_out; ++s) {
        __syncthreads();  // barrier A: slot posts of this parity visible
        const int par = s & 1;

        const unsigned long long k0 = sm.slots[par][lane & 15];
        float M1;
        int G1;
        cross_slot_reduce(k0, M1, G1);
        const float thr = M1 - M1 * CERT_EPS;

        // owner publication + winner-m2 cert post: the unique owner thread
        // of the winning point posts xyz (all from registers) and its exact
        // second max over its own c[] (excluding the argmax slot qw).
        if (g1 == G1) {
            const int qw = (G1 - tid) >> 10;  // /1024
            float xw = 0.0f, yw = 0.0f, zw = 0.0f, m2w = -1.0f;
#pragma unroll
            for (int q = 0; q < P; ++q) {
                if (q == qw) { xw = xr[q]; yw = yr[q]; zw = zr[q]; }
                else m2w = fmaxf(m2w, c[q]);
            }
            sm.pub = make_float4(xw, yw, zw, 0.0f);
            sm.cw2[par][1] = (m2w >= thr) ? 1 : 0;
        }

        // resets for the next iteration's parity (race-free: next parity's
        // posts happen only after barrier B)
        if (tid < 16) sm.slots[par ^ 1][tid] = 0ull;
        if (tid == 0) { sm.cw2[par ^ 1][0] = 0; sm.cw2[par ^ 1][1] = 0; }

        // cert count (validated): #threads with m1>=thr via per-wave ballot
        // + one atomicAdd per wave.
        const unsigned long long bal = __ballot(m1 >= thr);
        if (lane == 0) atomicAdd(&sm.cw2[par][0], (int)__popcll(bal));

        __syncthreads();  // barrier B: pub + cert posts visible
        const int2 tw = *reinterpret_cast<const int2*>(&sm.cw2[par][0]);
        const int total = tw.x, wfl = tw.y;
        const float4 wc = sm.pub;
        float nx = wc.x, ny = wc.y, nz = wc.z;
        int wg = G1;

        if (total > 1 || wfl) {
            // ---- cooperative exact fp64 fallback (uniform branch, verbatim) ----
            unsigned miss = 0;
#pragma unroll
            for (int q = 0; q < P; ++q)
                if (c[q] >= thr) miss |= (1u << q);
            double BD = -1.0;
            int BG = 0x7fffffff;
            for (;;) {
                if (tid == 0) { sm.cand_cnt = 0; sm.more_flag = 0; }
                __syncthreads();
#pragma unroll
                for (int q = 0; q < P; ++q) {
                    if (miss & (1u << q)) {
                        int slot = atomicAdd(&sm.cand_cnt, 1);
                        if (slot < 64) {
                            sm.cand_idx[slot] = tid + q * T;
                            miss &= ~(1u << q);
                        } else {
                            sm.more_flag = 1;
                        }
                    }
                }
                __syncthreads();
                int ncand = sm.cand_cnt;
                if (ncand > 64) ncand = 64;
                for (int ci = 0; ci < ncand; ++ci) {
                    const int g = sm.cand_idx[ci];
                    const double qx = (double)pts[g * 3 + 0];
                    const double qy = (double)pts[g * 3 + 1];
                    const double qz = (double)pts[g * 3 + 2];
                    double dmin = DBL_MAX;
                    for (int i = tid; i < s; i += T) {
                        const int h = fi[i];
                        double ddx = qx - (double)pts[h * 3 + 0];
                        double ddy = qy - (double)pts[h * 3 + 1];
                        double ddz = qz - (double)pts[h * 3 + 2];
                        double dd = ddx * ddx + ddy * ddy + ddz * ddz;
                        dmin = (dd < dmin) ? dd : dmin;
                    }
                    for (int off = 32; off; off >>= 1) {
                        double od = __shfl_xor(dmin, off);
                        dmin = (od < dmin) ? od : dmin;
                    }
                    if (lane == 0) sm.red_d[wave] = dmin;
                    __syncthreads();
                    double dall = sm.red_d[0];
#pragma unroll
                    for (int w = 1; w < NW; ++w) dall = (sm.red_d[w] < dall) ? sm.red_d[w] : dall;
                    if (dall > BD || (dall == BD && g < BG)) { BD = dall; BG = g; }
                    __syncthreads();
                }
                int mf = sm.more_flag;
                __syncthreads();
                if (!mf) break;
            }
            wg = BG;
            nx = pts[wg * 3 + 0];
            ny = pts[wg * 3 + 1];
            nz = pts[wg * 3 + 2];
        }

        if (tid == 0) fi[s] = wg;
        if (s == n_out - 1) break;

        // fused min-update + per-thread argmax (validated numerics; winner
        // m2 recomputed exactly by the owner above).
        float nm1 = -1.0f;
        int ng1 = 0x7fffffff;
#pragma unroll
        for (int q = 0; q < P; ++q) {
            const float dx = xr[q] - nx, dy = yr[q] - ny, dz = zr[q] - nz;
            const float t = fmaf(dx, dx, fmaf(dy, dy, dz * dz));
            const float nc = fminf(c[q], t);
            c[q] = nc;
            const bool gt = nc > nm1;
            nm1 = fmaxf(nm1, nc);
            ng1 = gt ? (tid + q * T) : ng1;
        }
        m1 = nm1; g1 = ng1;
        const unsigned long long key =
            ((unsigned long long)__float_as_uint(m1) << 32) |
            (unsigned long long)(~(unsigned)g1);
        atomicMax(&sm.slots[par ^ 1][tid & 15], key);
    }
}

// ---------------------------------------------------------------------------
// Fused KNN + EdgeConv body: 1024 threads = 16 waves = 16 query points.
// Per-wave fp64-exact top-16 (verbatim). EdgeConv h2 via per-wave LDS h1
// staging + broadcast float4 reads (R6-R11 validated, bit-identical fmaf
// order).
// ---------------------------------------------------------------------------
struct KnnSmem {
    float sx[KNN_TILE], sy[KNN_TILE], sz[KNN_TILE];
    float w1[6 * 64], b1v[64], w2[64 * 64], b2v[64];
    __align__(16) float h1buf[16][64];
};

__device__ __forceinline__ void knn_edge_body(
    KnnSmem& sm, const float* __restrict__ pts,
    const float* __restrict__ ew1, const float* __restrict__ eb1,
    const float* __restrict__ ew2, const float* __restrict__ eb2,
    float* __restrict__ feats, int qb) {
    for (int t = threadIdx.x; t < 6 * 64; t += 1024) sm.w1[t] = ew1[t];
    for (int t = threadIdx.x; t < 64; t += 1024) { sm.b1v[t] = eb1[t]; sm.b2v[t] = eb2[t]; }
    for (int t = threadIdx.x; t < 64 * 64; t += 1024) sm.w2[t] = ew2[t];

    const int wave = threadIdx.x >> 6;
    const int lane = threadIdx.x & 63;
    const int qi = qb * 16 + wave;
    const double qxd = (double)pts[qi * 3 + 0];
    const double qyd = (double)pts[qi * 3 + 1];
    const double qzd = (double)pts[qi * 3 + 2];

    double ld[16];
    int li[16];
#pragma unroll
    for (int s = 0; s < 16; ++s) { ld[s] = DBL_MAX; li[s] = 0x7fffffff; }
    double md = DBL_MAX; int mj = 0x7fffffff; int mslot = 0;

    for (int t0 = 0; t0 < N_PTS; t0 += KNN_TILE) {
        __syncthreads();
        for (int t = threadIdx.x; t < KNN_TILE; t += 1024) {
            sm.sx[t] = pts[(t0 + t) * 3 + 0];
            sm.sy[t] = pts[(t0 + t) * 3 + 1];
            sm.sz[t] = pts[(t0 + t) * 3 + 2];
        }
        __syncthreads();
#pragma unroll
        for (int m = 0; m < KNN_TILE / 64; ++m) {
            const int cc = lane + m * 64;
            const int j = t0 + cc;
            if (j == qi) continue;  // diagonal excluded (d=inf in reference)
            double dx = qxd - (double)sm.sx[cc];
            double dy = qyd - (double)sm.sy[cc];
            double dz = qzd - (double)sm.sz[cc];
            double dd = dx * dx + dy * dy + dz * dz;
            if (dd < md || (dd == md && j < mj)) {
#pragma unroll
                for (int s = 0; s < 16; ++s)
                    if (s == mslot) { ld[s] = dd; li[s] = j; }
                md = -1.0; mj = -1; mslot = 0;
#pragma unroll
                for (int s = 0; s < 16; ++s) {
                    bool g = (ld[s] > md) || (ld[s] == md && li[s] > mj);
                    if (g) { md = ld[s]; mj = li[s]; mslot = s; }
                }
            }
        }
    }

    const float xi = pts[qi * 3], yi = pts[qi * 3 + 1], zi = pts[qi * 3 + 2];
    float acc = -FLT_MAX;
    for (int r = 0; r < KNN_K; ++r) {
        double cd = DBL_MAX; int cj = 0x7fffffff; int cs = 0;
#pragma unroll
        for (int s = 0; s < 16; ++s) {
            bool l = (ld[s] < cd) || (ld[s] == cd && li[s] < cj);
            if (l) { cd = ld[s]; cj = li[s]; cs = s; }
        }
        double wd = cd; int wj = cj;
        for (int off = 32; off; off >>= 1) {
            double od = __shfl_xor(wd, off);
            int oj = __shfl_xor(wj, off);
            if (od < wd || (od == wd && oj < wj)) { wd = od; wj = oj; }
        }
        if (cd == wd && cj == wj) {
#pragma unroll
            for (int s = 0; s < 16; ++s)
                if (s == cs) { ld[s] = DBL_MAX; li[s] = 0x7fffffff; }
        }
        const float xj = pts[wj * 3], yj = pts[wj * 3 + 1], zj = pts[wj * 3 + 2];
        const float f3 = xj - xi, f4 = yj - yi, f5 = zj - zi;
        float h1 = sm.b1v[lane];
        h1 = fmaf(xi, sm.w1[0 * 64 + lane], h1);
        h1 = fmaf(yi, sm.w1[1 * 64 + lane], h1);
        h1 = fmaf(zi, sm.w1[2 * 64 + lane], h1);
        h1 = fmaf(f3, sm.w1[3 * 64 + lane], h1);
        h1 = fmaf(f4, sm.w1[4 * 64 + lane], h1);
        h1 = fmaf(f5, sm.w1[5 * 64 + lane], h1);
        h1 = fmaxf(h1, 0.0f);
        // stage h1 to this wave's LDS row; read back broadcast float4.
        // fmaf order d = 0..63 preserved -> bit-identical to __shfl version.
        sm.h1buf[wave][lane] = h1;
        float h2 = sm.b2v[lane];
        const float4* h4 = reinterpret_cast<const float4*>(&sm.h1buf[wave][0]);
#pragma unroll
        for (int dd = 0; dd < 16; ++dd) {
            const float4 hv = h4[dd];
            h2 = fmaf(hv.x, sm.w2[(dd * 4 + 0) * 64 + lane], h2);
            h2 = fmaf(hv.y, sm.w2[(dd * 4 + 1) * 64 + lane], h2);
            h2 = fmaf(hv.z, sm.w2[(dd * 4 + 2) * 64 + lane], h2);
            h2 = fmaf(hv.w, sm.w2[(dd * 4 + 3) * 64 + lane], h2);
        }
        acc = fmaxf(acc, h2);
    }
    feats[qi * 64 + lane] = acc;
}

// ---------------------------------------------------------------------------
// Mega kernel: block 0 = single FPS stage (prefix property: fi1/fi2 are
// prefixes of fi0) + sp writeback. Blocks 1..1024 = fused knn+edgeconv,
// hidden under fps.
// LDS is PADDED past 80 KB so only ONE block fits per CU: block 0 (the
// 5.6 ms serial FPS chain) gets a PRIVATE CU with no co-resident KNN block
// stealing issue slots. KNN is fp64-throughput-bound, so 1 block/CU keeps
// its wall time ~unchanged (4 rounds x T1 ~= 2 rounds x 2*T1) and it stays
// fully hidden under FPS.
// ---------------------------------------------------------------------------
__global__ __launch_bounds__(1024)
void mega_kernel(const float* __restrict__ pts,
                 const float* __restrict__ ew1, const float* __restrict__ eb1,
                 const float* __restrict__ ew2, const float* __restrict__ eb2,
                 float* __restrict__ feats,
                 int* __restrict__ fi0,
                 float* __restrict__ sp0, float* __restrict__ sp1,
                 float* __restrict__ sp2) {
    constexpr size_t SMEM_UNION =
        sizeof(FpsSmem) > sizeof(KnnSmem) ? sizeof(FpsSmem) : sizeof(KnnSmem);
    constexpr size_t SMEM_PAD = 84 * 1024;  // > 160/2 KB -> 1 block/CU
    constexpr size_t SMEM_BYTES = SMEM_UNION > SMEM_PAD ? SMEM_UNION : SMEM_PAD;
    __shared__ __align__(16) char raw[SMEM_BYTES];
    if (blockIdx.x == 0) {
        FpsSmem& sm = *reinterpret_cast<FpsSmem*>(raw);
        fps_run(sm, pts, 4096, fi0);
        __syncthreads();
        const int tid = threadIdx.x;
        for (int t = tid; t < 4096; t += 1024) {
            const int g = fi0[t];
            const float x = pts[g * 3 + 0];
            const float y = pts[g * 3 + 1];
            const float z = pts[g * 3 + 2];
            sp0[t * 3 + 0] = x;
            sp0[t * 3 + 1] = y;
            sp0[t * 3 + 2] = z;
            if (t < 1024) {
                sp1[t * 3 + 0] = x;
                sp1[t * 3 + 1] = y;
                sp1[t * 3 + 2] = z;
            }
            if (t < 256) {
                sp2[t * 3 + 0] = x;
                sp2[t * 3 + 1] = y;
                sp2[t * 3 + 2] = z;
            }
        }
    } else {
        knn_edge_body(*reinterpret_cast<KnnSmem*>(raw), pts, ew1, eb1, ew2, eb2,
                      feats, blockIdx.x - 1);
    }
}

// ---------------------------------------------------------------------------
// Tail: all three MLPs in one launch (validated mlp numerics, verbatim).
// All stages index feats via fi0 prefixes (prefix property).
// ---------------------------------------------------------------------------
__device__ __forceinline__ void mlp_body(
    const float* __restrict__ feats, const int* __restrict__ orig,
    const float* __restrict__ mw1, const float* __restrict__ mb1,
    const float* __restrict__ mw2, const float* __restrict__ mb2,
    float* __restrict__ outp, int pb) {
    __shared__ float sfl[64], h1l[128];
    const int t = threadIdx.x;
    for (int pl = 0; pl < 16; ++pl) {
        const int p = pb * 16 + pl;
        const int g = orig[p];
        if (t < 64) sfl[t] = feats[g * 64 + t];
        __syncthreads();
        if (t < 128) {
            float h = mb1[t];
            for (int dd = 0; dd < 64; ++dd)
                h = fmaf(sfl[dd], mw1[dd * 128 + t], h);
            h1l[t] = fmaxf(h, 0.0f);
        }
        __syncthreads();
        float o = mb2[t];
        for (int dd = 0; dd < 128; ++dd)
            o = fmaf(h1l[dd], mw2[dd * 256 + t], o);
        outp[p * 256 + t] = o;
        __syncthreads();
    }
}

__global__ __launch_bounds__(256) void tail_kernel(
    const float* __restrict__ feats,
    const int* __restrict__ fi0,
    const float* __restrict__ mw1, const float* __restrict__ mb1,
    const float* __restrict__ mw2, const float* __restrict__ mb2,
    float* __restrict__ out) {
    const int b = blockIdx.x;
    float* lf0 = out + 12288;
    float* lf1 = out + 1063936;
    float* lf2 = out + 1326848;
    if (b < 256) {
        mlp_body(feats, fi0, mw1 + 0 * 8192, mb1 + 0 * 128,
                 mw2 + 0 * 32768, mb2 + 0 * 256, lf0, b);
    } else if (b < 320) {
        mlp_body(feats, fi0, mw1 + 1 * 8192, mb1 + 1 * 128,
                 mw2 + 1 * 32768, mb2 + 1 * 256, lf1, b - 256);
    } else {
        mlp_body(feats, fi0, mw1 + 2 * 8192, mb1 + 2 * 128,
                 mw2 + 2 * 32768, mb2 + 2 * 256, lf2, b - 320);
    }
}

// ---------------------------------------------------------------------------
extern "C" void kernel_launch(void* const* d_in, const int* in_sizes, int n_in,
                              void* d_out, int out_size, void* d_ws, size_t ws_size,
                              hipStream_t stream) {
    const float* pts = (const float*)d_in[0];
    const float* ew1 = (const float*)d_in[1];
    const float* eb1 = (const float*)d_in[2];
    const float* ew2 = (const float*)d_in[3];
    const float* eb2 = (const float*)d_in[4];
    const float* mw1 = (const float*)d_in[5];  // (3,64,128)
    const float* mb1 = (const float*)d_in[6];  // (3,128)
    const float* mw2 = (const float*)d_in[7];  // (3,128,256)
    const float* mb2 = (const float*)d_in[8];  // (3,256)
    float* out = (float*)d_out;
    char* ws = (char*)d_ws;

    float* feats = (float*)(ws + 0);           // 16384*64*4 = 4 MB
    int* fi0 = (int*)(ws + 4194304);           // 4096 ints (original indices)

    float* sp0 = out + 0;
    float* sp1 = out + 1060864;
    float* sp2 = out + 1326080;

    mega_kernel<<<1 + N_PTS / 16, 1024, 0, stream>>>(pts, ew1, eb1, ew2, eb2, feats,
                                                     fi0, sp0, sp1, sp2);
    tail_kernel<<<336, 256, 0, stream>>>(feats, fi0, mw1, mb1, mw2, mb2, out);
}